// Round 5
// baseline (1496.025 us; speedup 1.0000x reference)
//
#include <hip/hip_runtime.h>

typedef __attribute__((ext_vector_type(8))) short bf16x8;
typedef __attribute__((ext_vector_type(4))) float f32x4;
typedef unsigned short u16;

#define MFMA16(a, b, c) __builtin_amdgcn_mfma_f32_16x16x32_bf16(a, b, c, 0, 0, 0)

#define S_LEN 9216
#define CIN   512
#define KC    256
#define VC    256
#define CO    512
#define NB    2
#define KVBLK   32
#define KVTILES (S_LEN / KVBLK)              // 288
#define KSPLIT  8
#define TILES_PER_SPLIT (KVTILES / KSPLIT)   // 36
#define NS (NB * S_LEN)

// RNE float -> bf16 bits
__device__ __forceinline__ u16 f2b(float f) {
    union { float f; unsigned u; } un; un.f = f;
    unsigned r = un.u + 0x7fffu + ((un.u >> 16) & 1u);
    return (u16)(r >> 16);
}
__device__ __forceinline__ float b2f(u16 b) {
    union { unsigned u; float f; } un; un.u = ((unsigned)b) << 16;
    return un.f;
}

// async global->LDS, 16B per lane; LDS dest = wave-uniform base + lane*16
__device__ __forceinline__ void gload_lds16(const u16* g, u16* l) {
    __builtin_amdgcn_global_load_lds(
        (const __attribute__((address_space(1))) unsigned*)g,
        (__attribute__((address_space(3))) unsigned*)l, 16, 0, 0);
}

// ---------------------------------------------------------------------------
// weight prep: fold BN into Wk, convert weights to bf16
// ---------------------------------------------------------------------------
__global__ __launch_bounds__(256)
void prep_weights(const float* __restrict__ Wk, const float* __restrict__ bk,
                  const float* __restrict__ gamma, const float* __restrict__ beta,
                  const float* __restrict__ rmean, const float* __restrict__ rvar,
                  const float* __restrict__ Wv, const float* __restrict__ Ww,
                  u16* __restrict__ Wkb, u16* __restrict__ Wvb,
                  u16* __restrict__ Wwb, float* __restrict__ bkf) {
    int i = blockIdx.x * 256 + threadIdx.x;
    if (i < KC * CIN) {
        int kc = i >> 9;  // /512
        float scale = gamma[kc] * rsqrtf(rvar[kc] + 1e-5f);
        Wkb[i] = f2b(Wk[i] * scale);
        Wvb[i] = f2b(Wv[i]);
    }
    if (i < CO * VC) Wwb[i] = f2b(Ww[i]);
    if (i < KC) {
        float scale = gamma[i] * rsqrtf(rvar[i] + 1e-5f);
        bkf[i] = bk[i] * scale + beta[i] - rmean[i] * scale;
    }
}

// ---------------------------------------------------------------------------
// transpose: x [N][C][S] f32  ->  xT [N][S][C] bf16
// ---------------------------------------------------------------------------
__global__ __launch_bounds__(256)
void transpose_x(const float* __restrict__ x, u16* __restrict__ xT) {
    __shared__ float t[32][33];
    const int s0 = blockIdx.x * 32, c0 = blockIdx.y * 32, n = blockIdx.z;
    const int tx = threadIdx.x, ty = threadIdx.y;
    const float* xb = x + (size_t)n * CIN * S_LEN;
#pragma unroll
    for (int i = 0; i < 4; ++i)
        t[ty + 8 * i][tx] = xb[(size_t)(c0 + ty + 8 * i) * S_LEN + s0 + tx];
    __syncthreads();
    u16* xo = xT + (size_t)n * S_LEN * CIN;
#pragma unroll
    for (int i = 0; i < 4; ++i)
        xo[(size_t)(s0 + ty + 8 * i) * CIN + c0 + tx] = f2b(t[tx][ty + 8 * i]);
}

// ---------------------------------------------------------------------------
// NT GEMM: D[i][j] = sum_k A[i][k] * B[j][k]   (A:[M][K], B:[N][K] bf16)
// EPI 0: +bias[col], relu, bf16 out   (k-projection)
// EPI 1: +bias[row], bf16 out         (v-projection)
// EPI 2: +bias[row], f32 out          (output projection)
// ---------------------------------------------------------------------------
template <int EPI>
__global__ __launch_bounds__(256)
void gemm_nt(const u16* __restrict__ A, const u16* __restrict__ B,
             const float* __restrict__ bias, void* __restrict__ Dout,
             int K, int ldd, size_t strideB, size_t strideD) {
    const int z = blockIdx.z;
    B += strideB * z;
    const int bm = blockIdx.x * 64;
    const int bn = blockIdx.y * 64;
    const int tid = threadIdx.x;
    const int wave = tid >> 6, lane = tid & 63, lr = lane & 15, lg = lane >> 4;
    const int wm = (wave >> 1) * 32, wn = (wave & 1) * 32;

    f32x4 acc[2][2];
#pragma unroll
    for (int i = 0; i < 2; ++i)
#pragma unroll
        for (int j = 0; j < 2; ++j) acc[i][j] = (f32x4){0.f, 0.f, 0.f, 0.f};

    for (int k0 = 0; k0 < K; k0 += 32) {
        bf16x8 af[2], bfr[2];
#pragma unroll
        for (int i = 0; i < 2; ++i)
            af[i] = *(const bf16x8*)(A + (size_t)(bm + wm + i * 16 + lr) * K + k0 + lg * 8);
#pragma unroll
        for (int j = 0; j < 2; ++j)
            bfr[j] = *(const bf16x8*)(B + (size_t)(bn + wn + j * 16 + lr) * K + k0 + lg * 8);
#pragma unroll
        for (int i = 0; i < 2; ++i)
#pragma unroll
            for (int j = 0; j < 2; ++j)
                acc[i][j] = MFMA16(af[i], bfr[j], acc[i][j]);
    }

#pragma unroll
    for (int i = 0; i < 2; ++i)
#pragma unroll
        for (int j = 0; j < 2; ++j)
#pragma unroll
            for (int r = 0; r < 4; ++r) {
                int row = bm + wm + i * 16 + lg * 4 + r;
                int col = bn + wn + j * 16 + lr;
                float val = acc[i][j][r] + (EPI == 0 ? bias[col] : bias[row]);
                if (EPI == 0) val = fmaxf(val, 0.f);
                if (EPI == 2)
                    ((float*)Dout)[strideD * z + (size_t)row * ldd + col] = val;
                else
                    ((u16*)Dout)[strideD * z + (size_t)row * ldd + col] = f2b(val);
            }
}

// ---------------------------------------------------------------------------
// flash attention, split-KV, KVBLK=32, swapped QK^T (lane-local softmax).
// Q,K from kT [N][S][256] bf16; V from v [N][256][S] bf16.
// Each block: one 64-row Q tile x one KV split (36 kv tiles of 32).
// LDS 36KB/block -> 4 blocks/CU. S^T = mfma(A=K, B=Q) so each lane owns
// q=lane&15 with kv = kvt*16 + lg*4 + r in regs: softmax = in-lane reduce
// + 2 shfl_xor. Writes unnormalized partial acc (bf16) + (m,l) (f32).
// ---------------------------------------------------------------------------
__global__ __launch_bounds__(256, 4)
void attn_kernel(const u16* __restrict__ kT, const u16* __restrict__ vmat,
                 u16* __restrict__ accP, float* __restrict__ ml) {
    const int qt = blockIdx.x;
    const int split = blockIdx.y;
    const int n = blockIdx.z;
    const int q0 = qt * 64;
    const u16* Kb = kT + (size_t)n * S_LEN * KC;
    const u16* Vb = vmat + (size_t)n * VC * S_LEN;

    const int tid = threadIdx.x;
    const int wave = tid >> 6;
    const int lane = tid & 63;
    const int lr = lane & 15;
    const int lg = lane >> 4;

    __shared__ __align__(16) u16 Klds[KVBLK * 256];     // 16KB, rows 512B, swz (row&7)<<4
    __shared__ __align__(16) u16 Vlds[256 * KVBLK];     // 16KB, rows 64B,  swz (vc&3)<<4
    __shared__ __align__(16) u16 Plds[4][16 * KVBLK];   // 4KB per-wave, rows 64B, swz (q&3)<<4

    // Q B-frags (col=q=lr, k=lg*8+i) — 16 q-rows per wave, K=256
    bf16x8 qf[8];
    {
        const u16* qrow = Kb + (size_t)(q0 + wave * 16 + lr) * KC + lg * 8;
#pragma unroll
        for (int ks = 0; ks < 8; ++ks) qf[ks] = *(const bf16x8*)(qrow + ks * 32);
    }

    f32x4 acc[16];
#pragma unroll
    for (int i = 0; i < 16; ++i) acc[i] = (f32x4){0.f, 0.f, 0.f, 0.f};
    float m_run = -1e30f, l_run = 0.f;   // per-lane, for q = lr

    const int kv_lo = split * TILES_PER_SPLIT;
    for (int kv = kv_lo; kv < kv_lo + TILES_PER_SPLIT; ++kv) {
        const int s0 = kv * KVBLK;
        __syncthreads();   // previous tile's compute done before overwrite
        // stage K (32 rows x 512B) + V (256 rows x 64B): linear LDS dest,
        // inverse-swizzled global source (both XORs are involutions).
#pragma unroll
        for (int c = 0; c < 4; ++c) {
            int o = ((c * 4 + wave) * 64 + lane) * 16;
            {   // K
                int row = o >> 9;
                int cu = (o & 511) ^ ((row & 7) << 4);
                gload_lds16(Kb + (size_t)(s0 + row) * KC + (cu >> 1),
                            &Klds[(c * 4 + wave) * 512]);
            }
            {   // V
                int vc = o >> 6;
                int cu = (o & 63) ^ ((vc & 3) << 4);
                gload_lds16(Vb + (size_t)vc * S_LEN + s0 + (cu >> 1),
                            &Vlds[(c * 4 + wave) * 512]);
            }
        }
        __syncthreads();   // drains vmcnt before any wave reads LDS

        // S^T = K · Q^T : A = K-frag (rows=kv), B = Q (cols=q)
        f32x4 sfr[2];
#pragma unroll
        for (int kvt = 0; kvt < 2; ++kvt) sfr[kvt] = (f32x4){0.f, 0.f, 0.f, 0.f};
#pragma unroll
        for (int ks = 0; ks < 8; ++ks) {
#pragma unroll
            for (int kvt = 0; kvt < 2; ++kvt) {
                int row = kvt * 16 + lr;
                int byte = (row * 512 + (ks * 32 + lg * 8) * 2) ^ ((row & 7) << 4);
                bf16x8 kf = *(const bf16x8*)((char*)Klds + byte);
                sfr[kvt] = MFMA16(kf, qf[ks], sfr[kvt]);
            }
        }

        // lane-local online softmax: this lane owns q=lr, kv = kvt*16+lg*4+r
        float v[8], p[8];
#pragma unroll
        for (int kvt = 0; kvt < 2; ++kvt)
#pragma unroll
            for (int r = 0; r < 4; ++r) v[kvt * 4 + r] = sfr[kvt][r] * 0.0625f;
        float mt = v[0];
#pragma unroll
        for (int i = 1; i < 8; ++i) mt = fmaxf(mt, v[i]);
        mt = fmaxf(mt, __shfl_xor(mt, 16));
        mt = fmaxf(mt, __shfl_xor(mt, 32));
        float mnew = fmaxf(m_run, mt);
        float corr = __expf(m_run - mnew);
        m_run = mnew;
        float ps = 0.f;
#pragma unroll
        for (int i = 0; i < 8; ++i) { p[i] = __expf(v[i] - mnew); ps += p[i]; }
        ps += __shfl_xor(ps, 16);
        ps += __shfl_xor(ps, 32);
        l_run = l_run * corr + ps;

        // rescale acc rows q' = lg*4+r with corr from lane q'=lr side
        float cr[4];
#pragma unroll
        for (int r = 0; r < 4; ++r) cr[r] = __shfl(corr, lg * 4 + r);
#pragma unroll
        for (int ct = 0; ct < 16; ++ct)
#pragma unroll
            for (int r = 0; r < 4; ++r) acc[ct][r] *= cr[r];

        // write P to per-wave LDS (rows = q, 64B each, swz (q&3)<<4)
        char* pb = (char*)&Plds[wave][0];
#pragma unroll
        for (int kvt = 0; kvt < 2; ++kvt)
#pragma unroll
            for (int r = 0; r < 4; ++r) {
                int kvv = kvt * 16 + lg * 4 + r;
                *(u16*)(pb + ((lr * 64 + kvv * 2) ^ ((lr & 3) << 4))) = f2b(p[kvt * 4 + r]);
            }

        // PV: ctx[16 x 256] += P[16 x 32] * V[32 x 256]
        bf16x8 pf = *(const bf16x8*)(pb + ((lr * 64 + lg * 16) ^ ((lr & 3) << 4)));
#pragma unroll
        for (int ct = 0; ct < 16; ++ct) {
            int vc = ct * 16 + lr;
            bf16x8 vf = *(const bf16x8*)((char*)Vlds + ((vc * 64 + lg * 16) ^ ((vc & 3) << 4)));
            acc[ct] = MFMA16(pf, vf, acc[ct]);
        }
    }

    // epilogue: write unnormalized partial acc (bf16) + (m,l) per row
    const size_t pbase = (size_t)split * NS + (size_t)n * S_LEN + q0 + wave * 16;
#pragma unroll
    for (int r = 0; r < 4; ++r) {
        size_t rowaddr = (pbase + lg * 4 + r) * VC;
#pragma unroll
        for (int ct = 0; ct < 16; ++ct)
            accP[rowaddr + ct * 16 + lr] = f2b(acc[ct][r]);
    }
    if (lane < 16) {
        size_t rowidx = pbase + lane;
        ml[rowidx * 2 + 0] = m_run;
        ml[rowidx * 2 + 1] = l_run;
    }
}

// ---------------------------------------------------------------------------
// combine: merge KSPLIT partials -> ctx [N][S][VC] bf16
// ---------------------------------------------------------------------------
__global__ __launch_bounds__(256)
void combine_kernel(const u16* __restrict__ accP, const float* __restrict__ ml,
                    u16* __restrict__ ctx) {
    size_t idx = (size_t)blockIdx.x * 256 + threadIdx.x;  // NS * (VC/4) total
    int vc4 = (int)(idx & 63);
    size_t nrow = idx >> 6;
    float m[KSPLIT], l[KSPLIT];
    float M = -1e30f;
#pragma unroll
    for (int s = 0; s < KSPLIT; ++s) {
        m[s] = ml[((size_t)s * NS + nrow) * 2 + 0];
        l[s] = ml[((size_t)s * NS + nrow) * 2 + 1];
        M = fmaxf(M, m[s]);
    }
    float L = 0.f, w[KSPLIT];
#pragma unroll
    for (int s = 0; s < KSPLIT; ++s) {
        w[s] = __expf(m[s] - M);
        L += l[s] * w[s];
    }
    float invL = 1.0f / L;
    float o0 = 0.f, o1 = 0.f, o2 = 0.f, o3 = 0.f;
#pragma unroll
    for (int s = 0; s < KSPLIT; ++s) {
        ushort4 a = *(const ushort4*)(accP + ((size_t)s * NS + nrow) * VC + vc4 * 4);
        o0 += b2f(a.x) * w[s];
        o1 += b2f(a.y) * w[s];
        o2 += b2f(a.z) * w[s];
        o3 += b2f(a.w) * w[s];
    }
    ushort4 out;
    out.x = f2b(o0 * invL);
    out.y = f2b(o1 * invL);
    out.z = f2b(o2 * invL);
    out.w = f2b(o3 * invL);
    *(ushort4*)(ctx + nrow * VC + vc4 * 4) = out;
}

// ---------------------------------------------------------------------------
extern "C" void kernel_launch(void* const* d_in, const int* in_sizes, int n_in,
                              void* d_out, int out_size, void* d_ws, size_t ws_size,
                              hipStream_t stream) {
    const float* x     = (const float*)d_in[0];
    const float* Wk    = (const float*)d_in[1];
    const float* bk    = (const float*)d_in[2];
    const float* gamma = (const float*)d_in[3];
    const float* beta  = (const float*)d_in[4];
    const float* rmean = (const float*)d_in[5];
    const float* rvar  = (const float*)d_in[6];
    const float* Wv    = (const float*)d_in[7];
    const float* bv    = (const float*)d_in[8];
    const float* Ww    = (const float*)d_in[9];
    const float* bw    = (const float*)d_in[10];

    size_t off = 0;
    auto alloc = [&](size_t bytes) {
        void* p = (char*)d_ws + off;
        off += (bytes + 255) & ~(size_t)255;
        return p;
    };
    u16* xT   = (u16*)alloc((size_t)NB * S_LEN * CIN * 2);
    u16* kT   = (u16*)alloc((size_t)NB * S_LEN * KC * 2);
    u16* vm   = (u16*)alloc((size_t)NB * VC * S_LEN * 2);
    u16* ctx  = (u16*)alloc((size_t)NB * S_LEN * VC * 2);
    u16* Wkb  = (u16*)alloc((size_t)KC * CIN * 2);
    u16* Wvb  = (u16*)alloc((size_t)KC * CIN * 2);
    u16* Wwb  = (u16*)alloc((size_t)CO * VC * 2);
    float* bkf = (float*)alloc((size_t)KC * 4);
    u16* accP = (u16*)alloc((size_t)KSPLIT * NS * VC * 2);
    float* ml = (float*)alloc((size_t)KSPLIT * NS * 2 * 4);

    prep_weights<<<512, 256, 0, stream>>>(Wk, bk, gamma, beta, rmean, rvar, Wv, Ww,
                                          Wkb, Wvb, Wwb, bkf);
    transpose_x<<<dim3(S_LEN / 32, CIN / 32, NB), dim3(32, 8, 1), 0, stream>>>(x, xT);

    // kT[s][kc] = relu(bn(xT . Wk^T))  : M=N*S, N=KC, K=CIN
    gemm_nt<0><<<dim3(NB * S_LEN / 64, KC / 64, 1), 256, 0, stream>>>(
        xT, Wkb, bkf, kT, CIN, KC, 0, 0);
    // v[vc][s] = Wv . xT^T + bv        : M=VC, N=S, K=CIN, per batch
    gemm_nt<1><<<dim3(VC / 64, S_LEN / 64, NB), 256, 0, stream>>>(
        Wvb, xT, bv, vm, CIN, S_LEN, (size_t)S_LEN * CIN, (size_t)VC * S_LEN);

    attn_kernel<<<dim3(S_LEN / 64, KSPLIT, NB), 256, 0, stream>>>(kT, vm, accP, ml);
    combine_kernel<<<(NS * (VC / 4)) / 256, 256, 0, stream>>>(accP, ml, ctx);

    // out[co][s] = Ww . ctx^T + bw     : M=CO, N=S, K=VC, per batch, f32
    gemm_nt<2><<<dim3(CO / 64, S_LEN / 64, NB), 256, 0, stream>>>(
        Wwb, ctx, bw, d_out, VC, S_LEN, (size_t)S_LEN * VC, (size_t)CO * S_LEN);
}

// Round 6
// 519.015 us; speedup vs baseline: 2.8824x; 2.8824x over previous
//
#include <hip/hip_runtime.h>

typedef __attribute__((ext_vector_type(8))) short bf16x8;
typedef __attribute__((ext_vector_type(4))) float f32x4;
typedef unsigned short u16;

#define MFMA16(a, b, c) __builtin_amdgcn_mfma_f32_16x16x32_bf16(a, b, c, 0, 0, 0)

#define S_LEN 9216
#define CIN   512
#define KC    256
#define VC    256
#define CO    512
#define NB    2
#define KVBLK   64
#define QBLK    128
#define QTILES  (S_LEN / QBLK)               // 72
#define KVTILES (S_LEN / KVBLK)              // 144
#define KSPLIT  8
#define TILES_PER_SPLIT (KVTILES / KSPLIT)   // 18
#define NS (NB * S_LEN)
#define NBLK (QTILES * KSPLIT * NB)          // 1152

// RNE float -> bf16 bits
__device__ __forceinline__ u16 f2b(float f) {
    union { float f; unsigned u; } un; un.f = f;
    unsigned r = un.u + 0x7fffu + ((un.u >> 16) & 1u);
    return (u16)(r >> 16);
}
__device__ __forceinline__ float b2f(u16 b) {
    union { unsigned u; float f; } un; un.u = ((unsigned)b) << 16;
    return un.f;
}

// async global->LDS, 16B per lane; LDS dest = wave-uniform base + lane*16
__device__ __forceinline__ void gload_lds16(const u16* g, u16* l) {
    __builtin_amdgcn_global_load_lds(
        (const __attribute__((address_space(1))) unsigned*)g,
        (__attribute__((address_space(3))) unsigned*)l, 16, 0, 0);
}

// ---------------------------------------------------------------------------
// weight prep: fold BN into Wk, convert weights to bf16
// ---------------------------------------------------------------------------
__global__ __launch_bounds__(256)
void prep_weights(const float* __restrict__ Wk, const float* __restrict__ bk,
                  const float* __restrict__ gamma, const float* __restrict__ beta,
                  const float* __restrict__ rmean, const float* __restrict__ rvar,
                  const float* __restrict__ Wv, const float* __restrict__ Ww,
                  u16* __restrict__ Wkb, u16* __restrict__ Wvb,
                  u16* __restrict__ Wwb, float* __restrict__ bkf) {
    int i = blockIdx.x * 256 + threadIdx.x;
    if (i < KC * CIN) {
        int kc = i >> 9;  // /512
        float scale = gamma[kc] * rsqrtf(rvar[kc] + 1e-5f);
        Wkb[i] = f2b(Wk[i] * scale);
        Wvb[i] = f2b(Wv[i]);
    }
    if (i < CO * VC) Wwb[i] = f2b(Ww[i]);
    if (i < KC) {
        float scale = gamma[i] * rsqrtf(rvar[i] + 1e-5f);
        bkf[i] = bk[i] * scale + beta[i] - rmean[i] * scale;
    }
}

// ---------------------------------------------------------------------------
// transpose: x [N][C][S] f32  ->  xT [N][S][C] bf16
// ---------------------------------------------------------------------------
__global__ __launch_bounds__(256)
void transpose_x(const float* __restrict__ x, u16* __restrict__ xT) {
    __shared__ float t[32][33];
    const int s0 = blockIdx.x * 32, c0 = blockIdx.y * 32, n = blockIdx.z;
    const int tx = threadIdx.x, ty = threadIdx.y;
    const float* xb = x + (size_t)n * CIN * S_LEN;
#pragma unroll
    for (int i = 0; i < 4; ++i)
        t[ty + 8 * i][tx] = xb[(size_t)(c0 + ty + 8 * i) * S_LEN + s0 + tx];
    __syncthreads();
    u16* xo = xT + (size_t)n * S_LEN * CIN;
#pragma unroll
    for (int i = 0; i < 4; ++i)
        xo[(size_t)(s0 + ty + 8 * i) * CIN + c0 + tx] = f2b(t[tx][ty + 8 * i]);
}

// ---------------------------------------------------------------------------
// NT GEMM: D[i][j] = sum_k A[i][k] * B[j][k]   (A:[M][K], B:[N][K] bf16)
// EPI 0: +bias[col], relu, bf16 out   (k-projection)
// EPI 1: +bias[row], bf16 out         (v-projection)
// EPI 2: +bias[row], f32 out          (output projection)
// ---------------------------------------------------------------------------
template <int EPI>
__global__ __launch_bounds__(256)
void gemm_nt(const u16* __restrict__ A, const u16* __restrict__ B,
             const float* __restrict__ bias, void* __restrict__ Dout,
             int K, int ldd, size_t strideB, size_t strideD) {
    const int z = blockIdx.z;
    B += strideB * z;
    const int bm = blockIdx.x * 64;
    const int bn = blockIdx.y * 64;
    const int tid = threadIdx.x;
    const int wave = tid >> 6, lane = tid & 63, lr = lane & 15, lg = lane >> 4;
    const int wm = (wave >> 1) * 32, wn = (wave & 1) * 32;

    f32x4 acc[2][2];
#pragma unroll
    for (int i = 0; i < 2; ++i)
#pragma unroll
        for (int j = 0; j < 2; ++j) acc[i][j] = (f32x4){0.f, 0.f, 0.f, 0.f};

    for (int k0 = 0; k0 < K; k0 += 32) {
        bf16x8 af[2], bfr[2];
#pragma unroll
        for (int i = 0; i < 2; ++i)
            af[i] = *(const bf16x8*)(A + (size_t)(bm + wm + i * 16 + lr) * K + k0 + lg * 8);
#pragma unroll
        for (int j = 0; j < 2; ++j)
            bfr[j] = *(const bf16x8*)(B + (size_t)(bn + wn + j * 16 + lr) * K + k0 + lg * 8);
#pragma unroll
        for (int i = 0; i < 2; ++i)
#pragma unroll
            for (int j = 0; j < 2; ++j)
                acc[i][j] = MFMA16(af[i], bfr[j], acc[i][j]);
    }

#pragma unroll
    for (int i = 0; i < 2; ++i)
#pragma unroll
        for (int j = 0; j < 2; ++j)
#pragma unroll
            for (int r = 0; r < 4; ++r) {
                int row = bm + wm + i * 16 + lg * 4 + r;
                int col = bn + wn + j * 16 + lr;
                float val = acc[i][j][r] + (EPI == 0 ? bias[col] : bias[row]);
                if (EPI == 0) val = fmaxf(val, 0.f);
                if (EPI == 2)
                    ((float*)Dout)[strideD * z + (size_t)row * ldd + col] = val;
                else
                    ((u16*)Dout)[strideD * z + (size_t)row * ldd + col] = f2b(val);
            }
}

// ---------------------------------------------------------------------------
// flash attention, split-KV, QBLK=128 (8 waves), KVBLK=64, double-buffered
// K/V staging with counted vmcnt, fully-swapped MFMAs (lane owns one q-row).
//   QK^T: S^T = mfma(A=K, B=Q)  -> lane (lr,lg): q=lr, kv = kvt*16+lg*4+r
//   PV  : ctx^T = mfma(A=V^T, B=P^T) -> lane: q=lr, vc = ct*16+lg*4+r
// P redistribution (D-frag -> B-frag) done in-register via shfl.
// Writes unnormalized partial acc (bf16) + per-row (m,l) (f32).
// ---------------------------------------------------------------------------
__global__ __launch_bounds__(512, 2)
void attn_kernel(const u16* __restrict__ kT, const u16* __restrict__ vmat,
                 u16* __restrict__ accP, float* __restrict__ ml) {
    // bijective XCD-chunked swizzle (NBLK % 8 == 0): each XCD gets a
    // contiguous chunk -> few concurrent (split,n) K/V streams per L2.
    const int flat = blockIdx.x;
    const int sw = (flat & 7) * (NBLK / 8) + (flat >> 3);
    const int qt = sw % QTILES;
    const int split = (sw / QTILES) & (KSPLIT - 1);
    const int n = sw / (QTILES * KSPLIT);
    const int q0 = qt * QBLK;
    const u16* Kb = kT + (size_t)n * S_LEN * KC;
    const u16* Vb = vmat + (size_t)n * VC * S_LEN;

    const int tid = threadIdx.x;
    const int wave = tid >> 6;
    const int lane = tid & 63;
    const int lr = lane & 15;
    const int lg = lane >> 4;

    __shared__ __align__(16) u16 Klds[2][KVBLK * 256];   // 2 x 32KB, swz (row&7)<<4
    __shared__ __align__(16) u16 Vlds[2][256 * KVBLK];   // 2 x 32KB, swz (vc&7)<<4

    // Q B-frags: 16 q-rows per wave (q = q0 + wave*16 + lr), K=256
    bf16x8 qf[8];
    {
        const u16* qrow = Kb + (size_t)(q0 + wave * 16 + lr) * KC + lg * 8;
#pragma unroll
        for (int ks = 0; ks < 8; ++ks) qf[ks] = *(const bf16x8*)(qrow + ks * 32);
    }
    // force Q loads to retire now so the waitcnt pass doesn't interleave
    // their drain with the pipelined staging below
    asm volatile("" : : "v"(qf[0]), "v"(qf[1]), "v"(qf[2]), "v"(qf[3]),
                        "v"(qf[4]), "v"(qf[5]), "v"(qf[6]), "v"(qf[7]));

    f32x4 acc[16];
#pragma unroll
    for (int i = 0; i < 16; ++i) acc[i] = (f32x4){0.f, 0.f, 0.f, 0.f};
    float m_run = -1e30f, l_run = 0.f;   // per-lane, q = lr

    const int kv_lo = split * TILES_PER_SPLIT;
    const int srcA = lr + ((lane & 16) ? 32 : 0);  // lane holding P words 0,1
    const int srcB = srcA + 16;                    // lane holding P words 2,3
    const bool kvhi = (lane & 32) != 0;            // kvt' = 2ks+1 ?

    // stage: 8 x gload_lds16 per lane per tile (4 K-chunks + 4 V-chunks)
    auto STAGE = [&](int buf, int kv) {
        const int s0 = kv * KVBLK;
        const u16* Ksrc = Kb + (size_t)s0 * KC;
#pragma unroll
        for (int c = 0; c < 4; ++c) {
            int j = c * 8 + wave;            // chunk 0..31, 1KB each
            int o = (j * 64 + lane) * 16;
            {   // K tile: 64 rows x 512B, inverse-swizzled source
                int row = o >> 9;
                int cu = (o & 511) ^ ((row & 7) << 4);
                gload_lds16(Ksrc + (size_t)row * KC + (cu >> 1), &Klds[buf][j * 512]);
            }
            {   // V tile: 256 rows x 128B
                int vc = o >> 7;
                int cu = (o & 127) ^ ((vc & 7) << 4);
                gload_lds16(Vb + (size_t)vc * S_LEN + s0 + (cu >> 1), &Vlds[buf][j * 512]);
            }
        }
    };

    auto COMPUTE = [&](int buf) {
        // S^T = K . Q^T over K=256
        f32x4 sfr[4];
#pragma unroll
        for (int kvt = 0; kvt < 4; ++kvt) sfr[kvt] = (f32x4){0.f, 0.f, 0.f, 0.f};
#pragma unroll
        for (int ks = 0; ks < 8; ++ks)
#pragma unroll
            for (int kvt = 0; kvt < 4; ++kvt) {
                int row = kvt * 16 + lr;
                int byte = (row * 512 + (ks * 32 + lg * 8) * 2) ^ ((row & 7) << 4);
                bf16x8 kf = *(const bf16x8*)((char*)Klds[buf] + byte);
                sfr[kvt] = MFMA16(kf, qf[ks], sfr[kvt]);
            }

        // lane-local online softmax for q=lr (16 kv values here; 64 across
        // lanes lr, lr+16, lr+32, lr+48)
        float p[4][4];
#pragma unroll
        for (int kvt = 0; kvt < 4; ++kvt)
#pragma unroll
            for (int r = 0; r < 4; ++r) p[kvt][r] = sfr[kvt][r] * 0.0625f;
        float mt = p[0][0];
#pragma unroll
        for (int kvt = 0; kvt < 4; ++kvt)
#pragma unroll
            for (int r = 0; r < 4; ++r) mt = fmaxf(mt, p[kvt][r]);
        mt = fmaxf(mt, __shfl_xor(mt, 16));
        mt = fmaxf(mt, __shfl_xor(mt, 32));
        // defer-max (THR=8): rescale only when max grew enough (wave-uniform)
        if (!__all(mt - m_run <= 8.0f)) {
            float mnew = fmaxf(m_run, mt);
            float corr = __expf(m_run - mnew);
            m_run = mnew;
            l_run *= corr;
#pragma unroll
            for (int ct = 0; ct < 16; ++ct)
#pragma unroll
                for (int r = 0; r < 4; ++r) acc[ct][r] *= corr;
        }
        float ps = 0.f;
#pragma unroll
        for (int kvt = 0; kvt < 4; ++kvt)
#pragma unroll
            for (int r = 0; r < 4; ++r) {
                float e = __expf(p[kvt][r] - m_run);
                p[kvt][r] = e;
                ps += e;
            }
        ps += __shfl_xor(ps, 16);
        ps += __shfl_xor(ps, 32);
        l_run += ps;

        // pack P to bf16 pairs: w[kvt][h] = (p[kvt][2h], p[kvt][2h+1])
        unsigned w[4][2];
#pragma unroll
        for (int kvt = 0; kvt < 4; ++kvt)
#pragma unroll
            for (int h = 0; h < 2; ++h)
                w[kvt][h] = (unsigned)f2b(p[kvt][2 * h]) |
                            ((unsigned)f2b(p[kvt][2 * h + 1]) << 16);

        // redistribute to B-frag: pa[ks][i] = P[q=lr][kv = ks*32 + lg*8 + i]
        union { int4 i4; bf16x8 b; } pu[2];
#pragma unroll
        for (int ks = 0; ks < 2; ++ks) {
            int a0 = __shfl((int)w[2 * ks][0], srcA);
            int b0 = __shfl((int)w[2 * ks + 1][0], srcA);
            int a1 = __shfl((int)w[2 * ks][1], srcA);
            int b1 = __shfl((int)w[2 * ks + 1][1], srcA);
            int a2 = __shfl((int)w[2 * ks][0], srcB);
            int b2 = __shfl((int)w[2 * ks + 1][0], srcB);
            int a3 = __shfl((int)w[2 * ks][1], srcB);
            int b3 = __shfl((int)w[2 * ks + 1][1], srcB);
            pu[ks].i4 = (int4){kvhi ? b0 : a0, kvhi ? b1 : a1,
                               kvhi ? b2 : a2, kvhi ? b3 : a3};
        }

        // ctx^T += V^T . P^T : acc[ct][r] = ctx[q=lr][vc=ct*16+lg*4+r]
#pragma unroll
        for (int ks = 0; ks < 2; ++ks) {
            bf16x8 paf = pu[ks].b;
#pragma unroll
            for (int ct = 0; ct < 16; ++ct) {
                int vc = ct * 16 + lr;
                int byte = (vc * 128 + (ks * 32 + lg * 8) * 2) ^ ((vc & 7) << 4);
                bf16x8 vf = *(const bf16x8*)((char*)Vlds[buf] + byte);
                acc[ct] = MFMA16(vf, paf, acc[ct]);
            }
        }
    };

    // 2-phase pipeline, counted vmcnt (8 loads in flight = next tile)
    STAGE(0, kv_lo);
#pragma unroll 1
    for (int t = 0; t < TILES_PER_SPLIT - 1; ++t) {
        const int cur = t & 1;
        STAGE(cur ^ 1, kv_lo + t + 1);
        asm volatile("s_waitcnt vmcnt(8)" ::: "memory");
        __builtin_amdgcn_sched_barrier(0);
        __builtin_amdgcn_s_barrier();
        COMPUTE(cur);
        __builtin_amdgcn_s_barrier();
    }
    asm volatile("s_waitcnt vmcnt(0)" ::: "memory");
    __builtin_amdgcn_sched_barrier(0);
    __builtin_amdgcn_s_barrier();
    COMPUTE((TILES_PER_SPLIT - 1) & 1);

    // epilogue: lane owns q = q0 + wave*16 + lr entirely
    const size_t qrow = (size_t)split * NS + (size_t)n * S_LEN + q0 + wave * 16 + lr;
    u16* outrow = accP + qrow * VC;
#pragma unroll
    for (int ct = 0; ct < 16; ++ct) {
        ushort4 o4;
        o4.x = f2b(acc[ct][0]);
        o4.y = f2b(acc[ct][1]);
        o4.z = f2b(acc[ct][2]);
        o4.w = f2b(acc[ct][3]);
        *(ushort4*)(outrow + ct * 16 + lg * 4) = o4;
    }
    if (lg == 0) {
        ml[qrow * 2 + 0] = m_run;
        ml[qrow * 2 + 1] = l_run;
    }
}

// ---------------------------------------------------------------------------
// combine: merge KSPLIT partials -> ctx [N][S][VC] bf16
// ---------------------------------------------------------------------------
__global__ __launch_bounds__(256)
void combine_kernel(const u16* __restrict__ accP, const float* __restrict__ ml,
                    u16* __restrict__ ctx) {
    size_t idx = (size_t)blockIdx.x * 256 + threadIdx.x;  // NS * (VC/4) total
    int vc4 = (int)(idx & 63);
    size_t nrow = idx >> 6;
    float m[KSPLIT], l[KSPLIT];
    float M = -1e30f;
#pragma unroll
    for (int s = 0; s < KSPLIT; ++s) {
        m[s] = ml[((size_t)s * NS + nrow) * 2 + 0];
        l[s] = ml[((size_t)s * NS + nrow) * 2 + 1];
        M = fmaxf(M, m[s]);
    }
    float L = 0.f, w[KSPLIT];
#pragma unroll
    for (int s = 0; s < KSPLIT; ++s) {
        w[s] = __expf(m[s] - M);
        L += l[s] * w[s];
    }
    float invL = 1.0f / L;
    float o0 = 0.f, o1 = 0.f, o2 = 0.f, o3 = 0.f;
#pragma unroll
    for (int s = 0; s < KSPLIT; ++s) {
        ushort4 a = *(const ushort4*)(accP + ((size_t)s * NS + nrow) * VC + vc4 * 4);
        o0 += b2f(a.x) * w[s];
        o1 += b2f(a.y) * w[s];
        o2 += b2f(a.z) * w[s];
        o3 += b2f(a.w) * w[s];
    }
    ushort4 out;
    out.x = f2b(o0 * invL);
    out.y = f2b(o1 * invL);
    out.z = f2b(o2 * invL);
    out.w = f2b(o3 * invL);
    *(ushort4*)(ctx + nrow * VC + vc4 * 4) = out;
}

// ---------------------------------------------------------------------------
extern "C" void kernel_launch(void* const* d_in, const int* in_sizes, int n_in,
                              void* d_out, int out_size, void* d_ws, size_t ws_size,
                              hipStream_t stream) {
    const float* x     = (const float*)d_in[0];
    const float* Wk    = (const float*)d_in[1];
    const float* bk    = (const float*)d_in[2];
    const float* gamma = (const float*)d_in[3];
    const float* beta  = (const float*)d_in[4];
    const float* rmean = (const float*)d_in[5];
    const float* rvar  = (const float*)d_in[6];
    const float* Wv    = (const float*)d_in[7];
    const float* bv    = (const float*)d_in[8];
    const float* Ww    = (const float*)d_in[9];
    const float* bw    = (const float*)d_in[10];

    size_t off = 0;
    auto alloc = [&](size_t bytes) {
        void* p = (char*)d_ws + off;
        off += (bytes + 255) & ~(size_t)255;
        return p;
    };
    u16* xT   = (u16*)alloc((size_t)NB * S_LEN * CIN * 2);
    u16* kT   = (u16*)alloc((size_t)NB * S_LEN * KC * 2);
    u16* vm   = (u16*)alloc((size_t)NB * VC * S_LEN * 2);
    u16* ctx  = (u16*)alloc((size_t)NB * S_LEN * VC * 2);
    u16* Wkb  = (u16*)alloc((size_t)KC * CIN * 2);
    u16* Wvb  = (u16*)alloc((size_t)KC * CIN * 2);
    u16* Wwb  = (u16*)alloc((size_t)CO * VC * 2);
    float* bkf = (float*)alloc((size_t)KC * 4);
    u16* accP = (u16*)alloc((size_t)KSPLIT * NS * VC * 2);
    float* ml = (float*)alloc((size_t)KSPLIT * NS * 2 * 4);

    prep_weights<<<512, 256, 0, stream>>>(Wk, bk, gamma, beta, rmean, rvar, Wv, Ww,
                                          Wkb, Wvb, Wwb, bkf);
    transpose_x<<<dim3(S_LEN / 32, CIN / 32, NB), dim3(32, 8, 1), 0, stream>>>(x, xT);

    // kT[s][kc] = relu(bn(xT . Wk^T))  : M=N*S, N=KC, K=CIN
    gemm_nt<0><<<dim3(NB * S_LEN / 64, KC / 64, 1), 256, 0, stream>>>(
        xT, Wkb, bkf, kT, CIN, KC, 0, 0);
    // v[vc][s] = Wv . xT^T + bv        : M=VC, N=S, K=CIN, per batch
    gemm_nt<1><<<dim3(VC / 64, S_LEN / 64, NB), 256, 0, stream>>>(
        Wvb, xT, bv, vm, CIN, S_LEN, (size_t)S_LEN * CIN, (size_t)VC * S_LEN);

    attn_kernel<<<NBLK, 512, 0, stream>>>(kT, vm, accP, ml);
    combine_kernel<<<(NS * (VC / 4)) / 256, 256, 0, stream>>>(accP, ml, ctx);

    // out[co][s] = Ww . ctx^T + bw     : M=CO, N=S, K=VC, per batch, f32
    gemm_nt<2><<<dim3(CO / 64, S_LEN / 64, NB), 256, 0, stream>>>(
        Wwb, ctx, bw, d_out, VC, S_LEN, (size_t)S_LEN * VC, (size_t)CO * S_LEN);
}